// Round 10
// baseline (48.502 us; speedup 1.0000x reference)
//
#include <hip/hip_runtime.h>
#include <hip/hip_bf16.h>

#define HW 128
#define PW 130   // padded width/height

typedef float f32x4 __attribute__((ext_vector_type(4)));
typedef short bf16x8 __attribute__((ext_vector_type(8)));

__device__ __forceinline__ unsigned short f2bf(float v) {
  __hip_bfloat16 h = __float2bfloat16(v);
  return *reinterpret_cast<unsigned short*>(&h);
}

__device__ __forceinline__ void bf8_to_f32(const int4& r, float* f) {
  const unsigned int* u = reinterpret_cast<const unsigned int*>(&r);
#pragma unroll
  for (int k = 0; k < 4; ++k) {
    f[2 * k]     = __uint_as_float(u[k] << 16);
    f[2 * k + 1] = __uint_as_float(u[k] & 0xffff0000u);
  }
}

__device__ __forceinline__ void gld_lds16(const void* g, void* l) {
  __builtin_amdgcn_global_load_lds(
      (const __attribute__((address_space(1))) void*)g,
      (__attribute__((address_space(3))) void*)l, 16, 0, 0);
}

// ---------------- k_tr: prep + border-zero + NCHW->padded-NHWC transpose ----------------
// wfrag: main-GEMM B in MFMA fragment order:
//   frag f = t*8 + ot*2 + kk (ot = o-tile/16); elem i = f*512 + lane*8 + j
//   wfrag[i] = bf16(w[o=ot*16+(lane&15)][c=(kk*4+(lane>>4))*8+j][t])
// wb: offsets-conv B frags (r8-verified layout).
__global__ __launch_bounds__(256) void k_tr(const float* __restrict__ x,
                                            unsigned int* __restrict__ xt_u32,
                                            const float* __restrict__ w,
                                            const float* __restrict__ w_off,
                                            unsigned short* __restrict__ wfrag,
                                            unsigned short* __restrict__ wb) {
  __shared__ float tile[64 * 129];
  int blk = blockIdx.x;                   // b*128 + h
  int tid = threadIdx.x;
  int gi = blk * 256 + tid;

  // ---- folded prep ----
  if (blk < 144) {
    if (gi < 36864) {                     // 72 frags * 512
      int j = gi & 7, lane = (gi >> 3) & 63, f = gi >> 9;
      int kk = f & 1, ot = (f >> 1) & 3, t = f >> 3;
      int o = ot * 16 + (lane & 15);
      int c = (kk * 4 + (lane >> 4)) * 8 + j;
      wfrag[gi] = f2bf(w[o * 576 + c * 9 + t]);
    }
    if (gi < 18432) {
      int j = gi & 7, lane = (gi >> 3) & 63, f = gi >> 9;
      int n = f & 1, kk = (f >> 1) & 1, t = f >> 2;
      int o = n * 16 + (lane & 15);
      int c = kk * 32 + (lane >> 4) * 8 + j;
      float v = (o < 18) ? w_off[o * 576 + c * 9 + t] : 0.0f;
      wb[gi] = f2bf(v);
    }
  }
  // ---- folded border zero: 2064 cells * 8 int4 ----
  if (gi < 16512) {
    int c4 = gi & 7, ci = gi >> 3;
    int b = ci / 516, cell = ci - b * 516;
    int row, col;
    if (cell < 130)      { row = 0;   col = cell; }
    else if (cell < 260) { row = 129; col = cell - 130; }
    else { int k = cell - 260; row = 1 + (k >> 1); col = (k & 1) ? 129 : 0; }
    reinterpret_cast<int4*>(xt_u32 + ((size_t)(b * PW + row) * PW + col) * 32)[c4] =
        make_int4(0, 0, 0, 0);
  }

  // ---- transpose (r8-verified) ----
  int h = blk & 127, b = blk >> 7;
  int w0 = tid & 127, ch = tid >> 7;
  const float* xb = x + ((size_t)b * 64 * HW + h) * HW;
#pragma unroll
  for (int k = 0; k < 32; ++k) {
    int c = ch * 32 + k;
    tile[c * 129 + (w0 ^ (c & 1))] = xb[c * (HW * HW) + w0];
  }
  __syncthreads();
  int c2 = tid & 31, wg = tid >> 5;
#pragma unroll
  for (int k = 0; k < 16; ++k) {
    int ww = wg * 16 + k;
    float lo = tile[(2 * c2) * 129 + ww];
    float hi = tile[(2 * c2 + 1) * 129 + (ww ^ 1)];
    xt_u32[((size_t)(b * PW + h + 1) * PW + (ww + 1)) * 32 + c2] =
        (unsigned int)f2bf(lo) | ((unsigned int)f2bf(hi) << 16);
  }
}

// ---------------- k_fuse: slab-LDS offsets conv + slab-LDS gather + MFMA GEMM ----------------
// LDS (static, 64512 B, 2 blocks/CU):
//   slab [0, 43520)      5 rows x 68 cols x 128B  (padded rows r0..r0+4, cols c00..c00+67)
//   ldsA [43520, 59904)  2 x 8192 (sampled A dbuf)
//   loff [59904, 64512)  64 x 18 f32
// Main-GEMM B lives in registers (wfrag prefetch, 1 tap ahead) -> no ldsB, no in-loop vmcnt.
__global__ __launch_bounds__(256) void k_fuse(const unsigned short* __restrict__ xt,
                                              const unsigned short* __restrict__ wb,
                                              const unsigned short* __restrict__ wfrag,
                                              const float* __restrict__ b_off,
                                              const float* __restrict__ bias,
                                              float* __restrict__ out) {
  __shared__ __align__(16) char u_lds[64512];
  char* slab_b = u_lds;
  unsigned short* slab_us = (unsigned short*)u_lds;
  float* loff = (float*)(u_lds + 59904);

  int bid = blockIdx.x;
  bid = (bid & 7) * 128 + (bid >> 3);     // XCD swizzle (1024 % 8 == 0)
  int pix0 = bid * 64;
  int h = (pix0 >> 7) & 127, b = pix0 >> 14, wbase = pix0 & 127;
  int r0  = (h > 0) ? (h - 1) : 0;        // slab top padded row
  int c00 = (wbase > 0) ? (wbase - 1) : 0;// slab left padded col
  int dr = h - r0, dc = wbase - c00;      // 0 or 1

  int tid = threadIdx.x;
  int wid = tid >> 6, lane = tid & 63;
  int l15 = lane & 15, l4 = lane >> 4;
  int wm = wid >> 1, wn = wid & 1;
  int g = tid & 7, p2 = tid >> 3;

  const unsigned short* xb  = xt + (size_t)b * (PW * PW * 64);
  const unsigned short* xtb = xb + g * 8;

  // ---- stage 5x68 slab (clamped, all lanes active -> wave-uniform LDS base safe) ----
  for (int j2 = 0; j2 < 11; ++j2) {
    int ci = j2 * 256 + tid;              // chunk id: Sc*8 + c8
    if (ci < 2720) {                      // tail wave keeps lane 0 active
      int Sc = ci >> 3, c8 = ci & 7;
      int ly = Sc / 68, lx = Sc - ly * 68;
      int row = min(r0 + ly, 129), col = min(c00 + lx, 129);
      gld_lds16(xb + ((size_t)(row * PW + col)) * 64 + ((c8 ^ (Sc & 7)) << 3),
                slab_us + (size_t)ci * 8);
    }
  }

  // ---- phase 0: offsets conv from slab (B frags in regs) ----
  const int4* wb4 = reinterpret_cast<const int4*>(wb);
  int4 bc[4], bn[4];
#pragma unroll
  for (int q = 0; q < 4; ++q) bc[q] = wb4[q * 64 + lane];
  asm volatile("s_waitcnt vmcnt(0)" ::: "memory");
  __builtin_amdgcn_s_barrier();

  f32x4 acc0 = {0.f, 0.f, 0.f, 0.f}, acc1 = {0.f, 0.f, 0.f, 0.f};
#pragma unroll 1
  for (int t = 0; t < 9; ++t) {
    if (t < 8) {
#pragma unroll
      for (int q = 0; q < 4; ++q) bn[q] = wb4[((t + 1) * 4 + q) * 64 + lane];
    }
    int ti = t / 3, tj = t - ti * 3;
    int Sc = (ti + dr) * 68 + (wid * 16 + l15) + tj + dc;
#pragma unroll
    for (int kk = 0; kk < 2; ++kk) {
      int phys = (kk * 4 + l4) ^ (Sc & 7);
      bf16x8 a = *reinterpret_cast<const bf16x8*>(slab_b + Sc * 128 + phys * 16);
      acc0 = __builtin_amdgcn_mfma_f32_16x16x32_bf16(a, *(const bf16x8*)&bc[kk * 2 + 0], acc0, 0, 0, 0);
      acc1 = __builtin_amdgcn_mfma_f32_16x16x32_bf16(a, *(const bf16x8*)&bc[kk * 2 + 1], acc1, 0, 0, 0);
    }
#pragma unroll
    for (int q = 0; q < 4; ++q) bc[q] = bn[q];
  }
  {
    float bo0 = b_off[l15];
    int pl = wid * 16 + l4 * 4;
#pragma unroll
    for (int reg = 0; reg < 4; ++reg)
      loff[(pl + reg) * 18 + l15] = acc0[reg] + bo0;
    if (l15 < 2) {
      float bo1 = b_off[16 + l15];
#pragma unroll
      for (int reg = 0; reg < 4; ++reg)
        loff[(pl + reg) * 18 + 16 + l15] = acc1[reg] + bo1;
    }
  }
  __syncthreads();   // loff visible; slab stays read-only from here

  // ---- main loop helpers ----
  auto ldsAp = [&](int s) { return (unsigned short*)(u_lds + 43520 + s * 8192); };

  int4 r[2][4];
  float fw[2][4];

  auto gather = [&](int t) {
    int ti = t / 3, tj = t % 3;
#pragma unroll
    for (int k = 0; k < 2; ++k) {
      int pp = p2 + 32 * k;
      float2 d = *reinterpret_cast<const float2*>(&loff[pp * 18 + 2 * t]);
      float py = (float)(h + ti - 1) + d.x;
      float px = (float)(wbase + pp + tj - 1) + d.y;
      float y0f = floorf(py), x0f = floorf(px);
      float wy = py - y0f, wxf = px - x0f;
      int y0 = (int)y0f, x0 = (int)x0f;
      int y1 = y0 + 1, x1 = x0 + 1;
      fw[k][0] = (((unsigned)y0 < HW) && ((unsigned)x0 < HW)) ? (1.f - wy) * (1.f - wxf) : 0.f;
      fw[k][1] = (((unsigned)y0 < HW) && ((unsigned)x1 < HW)) ? (1.f - wy) * wxf : 0.f;
      fw[k][2] = (((unsigned)y1 < HW) && ((unsigned)x0 < HW)) ? wy * (1.f - wxf) : 0.f;
      fw[k][3] = (((unsigned)y1 < HW) && ((unsigned)x1 < HW)) ? wy * wxf : 0.f;
      int y0c = min(max(y0, 0), HW - 1) + 1, y1c = min(max(y1, 0), HW - 1) + 1;
      int x0c = min(max(x0, 0), HW - 1) + 1, x1c = min(max(x1, 0), HW - 1) + 1;
      int ly0 = y0c - r0, ly1 = y1c - r0;
      int lx0 = x0c - c00, lx1 = x1c - c00;
      bool ok = ((unsigned)ly0 <= 4u) && ((unsigned)ly1 <= 4u) &&
                ((unsigned)lx0 <= 67u) && ((unsigned)lx1 <= 67u);
      if (ok) {  // LDS path (normal case)
        int s00 = ly0 * 68 + lx0, s01 = ly0 * 68 + lx1;
        int s10 = ly1 * 68 + lx0, s11 = ly1 * 68 + lx1;
        r[k][0] = *reinterpret_cast<const int4*>(slab_b + s00 * 128 + ((g ^ (s00 & 7)) << 4));
        r[k][1] = *reinterpret_cast<const int4*>(slab_b + s01 * 128 + ((g ^ (s01 & 7)) << 4));
        r[k][2] = *reinterpret_cast<const int4*>(slab_b + s10 * 128 + ((g ^ (s10 & 7)) << 4));
        r[k][3] = *reinterpret_cast<const int4*>(slab_b + s11 * 128 + ((g ^ (s11 & 7)) << 4));
      } else {   // global fallback (large offsets)
        r[k][0] = *reinterpret_cast<const int4*>(xtb + ((size_t)y0c * PW + x0c) * 64);
        r[k][1] = *reinterpret_cast<const int4*>(xtb + ((size_t)y0c * PW + x1c) * 64);
        r[k][2] = *reinterpret_cast<const int4*>(xtb + ((size_t)y1c * PW + x0c) * 64);
        r[k][3] = *reinterpret_cast<const int4*>(xtb + ((size_t)y1c * PW + x1c) * 64);
      }
    }
  };

  auto lerp_write = [&](int bsel) {
#pragma unroll
    for (int k = 0; k < 2; ++k) {
      int pp = p2 + 32 * k;
      float v00[8], v01[8], v10[8], v11[8];
      bf8_to_f32(r[k][0], v00); bf8_to_f32(r[k][1], v01);
      bf8_to_f32(r[k][2], v10); bf8_to_f32(r[k][3], v11);
      unsigned int pk[4];
#pragma unroll
      for (int j = 0; j < 4; ++j) {
        float slo = fmaf(v11[2 * j], fw[k][3],
                    fmaf(v10[2 * j], fw[k][2],
                    fmaf(v01[2 * j], fw[k][1], v00[2 * j] * fw[k][0])));
        float shi = fmaf(v11[2 * j + 1], fw[k][3],
                    fmaf(v10[2 * j + 1], fw[k][2],
                    fmaf(v01[2 * j + 1], fw[k][1], v00[2 * j + 1] * fw[k][0])));
        pk[j] = (unsigned int)f2bf(slo) | ((unsigned int)f2bf(shi) << 16);
      }
      *reinterpret_cast<int4*>(&ldsAp(bsel)[pp * 64 + ((g ^ (pp & 7)) << 3)]) =
          *reinterpret_cast<int4*>(pk);
    }
  };

  // main-GEMM B frags: Bc[fn*2+kk], frag id = t*8 + (wn*2+fn)*2 + kk
  const int4* wf4 = reinterpret_cast<const int4*>(wfrag);
  int4 Bc[4], Bn[4];
#pragma unroll
  for (int q = 0; q < 4; ++q) {
    int fn = q >> 1, kk = q & 1;
    Bc[q] = wf4[((0 * 4 + wn * 2 + fn) * 2 + kk) * 64 + lane];
  }

  f32x4 acc00 = {0.f, 0.f, 0.f, 0.f}, acc01 = {0.f, 0.f, 0.f, 0.f};
  f32x4 acc10 = {0.f, 0.f, 0.f, 0.f}, acc11 = {0.f, 0.f, 0.f, 0.f};

  gather(0);
  lerp_write(0);
  __syncthreads();                 // A0 ready

#pragma unroll 1
  for (int t = 0; t < 9; ++t) {
    int cur = t & 1;
    if (t < 8) {
#pragma unroll
      for (int q = 0; q < 4; ++q) {
        int fn = q >> 1, kk = q & 1;
        Bn[q] = wf4[(((t + 1) * 4 + wn * 2 + fn) * 2 + kk) * 64 + lane];
      }
      gather(t + 1);
      lerp_write(cur ^ 1);
    }
    const char* Ab = (const char*)ldsAp(cur);
#pragma unroll
    for (int kk = 0; kk < 2; ++kk) {
      int sw = (((kk * 4 + l4) ^ (l15 & 7)) << 4) + l15 * 128;
      bf16x8 a0 = *(const bf16x8*)(Ab + (wm * 32 + 0)  * 128 + sw);
      bf16x8 a1 = *(const bf16x8*)(Ab + (wm * 32 + 16) * 128 + sw);
      acc00 = __builtin_amdgcn_mfma_f32_16x16x32_bf16(a0, *(const bf16x8*)&Bc[0 * 2 + kk], acc00, 0, 0, 0);
      acc01 = __builtin_amdgcn_mfma_f32_16x16x32_bf16(a0, *(const bf16x8*)&Bc[1 * 2 + kk], acc01, 0, 0, 0);
      acc10 = __builtin_amdgcn_mfma_f32_16x16x32_bf16(a1, *(const bf16x8*)&Bc[0 * 2 + kk], acc10, 0, 0, 0);
      acc11 = __builtin_amdgcn_mfma_f32_16x16x32_bf16(a1, *(const bf16x8*)&Bc[1 * 2 + kk], acc11, 0, 0, 0);
    }
#pragma unroll
    for (int q = 0; q < 4; ++q) Bc[q] = Bn[q];
    __syncthreads();
  }

  int m0 = wm * 32 + (l4 << 2);
#pragma unroll
  for (int fm = 0; fm < 2; ++fm) {
#pragma unroll
    for (int fn = 0; fn < 2; ++fn) {
      f32x4 a = (fm == 0) ? ((fn == 0) ? acc00 : acc01) : ((fn == 0) ? acc10 : acc11);
      int o = wn * 32 + fn * 16 + l15;
      int pix = pix0 + m0 + fm * 16;
      int bb = pix >> 14, hw = pix & 16383;
      float bz = bias[o];
      float4 st = make_float4(a[0] + bz, a[1] + bz, a[2] + bz, a[3] + bz);
      *reinterpret_cast<float4*>(&out[(((size_t)bb * 64 + o) << 14) + hw]) = st;
    }
  }
}

extern "C" void kernel_launch(void* const* d_in, const int* in_sizes, int n_in,
                              void* d_out, int out_size, void* d_ws, size_t ws_size,
                              hipStream_t stream) {
  const float* x     = (const float*)d_in[0];
  const float* w_off = (const float*)d_in[1];
  const float* b_off = (const float*)d_in[2];
  const float* w     = (const float*)d_in[3];
  const float* bias  = (const float*)d_in[4];
  float* out = (float*)d_out;
  char* ws   = (char*)d_ws;

  // ws layout (BYTES):
  //   wfrag [0,       73,728)      36,864 bf16 (main-GEMM B, frag-ordered)
  //   wb    [73,728,  110,592)     18,432 bf16 (offsets-conv B frags)
  //   xt    [110,592, 8,763,392)   4*130*130*64 bf16 (padded, zero border)
  unsigned short* wfrag = (unsigned short*)(ws);
  unsigned short* wb    = (unsigned short*)(ws + 73728);
  unsigned short* xt    = (unsigned short*)(ws + 110592);

  hipLaunchKernelGGL(k_tr,   dim3(512),  dim3(256), 0, stream,
                     x, (unsigned int*)xt, w, w_off, wfrag, wb);
  hipLaunchKernelGGL(k_fuse, dim3(1024), dim3(256), 0, stream,
                     xt, wb, wfrag, b_off, bias, out);
}

// Round 11
// 41.225 us; speedup vs baseline: 1.1765x; 1.1765x over previous
//
#include <hip/hip_runtime.h>
#include <hip/hip_bf16.h>

#define HW 128
#define PW 130   // padded width/height

typedef float f32x4 __attribute__((ext_vector_type(4)));
typedef short bf16x8 __attribute__((ext_vector_type(8)));

__device__ __forceinline__ unsigned short f2bf(float v) {
  __hip_bfloat16 h = __float2bfloat16(v);
  return *reinterpret_cast<unsigned short*>(&h);
}

__device__ __forceinline__ void bf8_to_f32(const int4& r, float* f) {
  const unsigned int* u = reinterpret_cast<const unsigned int*>(&r);
#pragma unroll
  for (int k = 0; k < 4; ++k) {
    f[2 * k]     = __uint_as_float(u[k] << 16);
    f[2 * k + 1] = __uint_as_float(u[k] & 0xffff0000u);
  }
}

__device__ __forceinline__ void gld_lds16(const void* g, void* l) {
  __builtin_amdgcn_global_load_lds(
      (const __attribute__((address_space(1))) void*)g,
      (__attribute__((address_space(3))) void*)l, 16, 0, 0);
}

// ---------------- k_tr: prep + border-zero + NCHW->padded-NHWC transpose ----------------
// wfrag: main-GEMM B in MFMA fragment order (r10-verified):
//   frag f = t*8 + ot*2 + kk; elem i = f*512 + lane*8 + j
//   wfrag[i] = bf16(w[o=ot*16+(lane&15)][c=(kk*4+(lane>>4))*8+j][t])
// wb: offsets-conv B frags (r8-verified layout).
__global__ __launch_bounds__(256) void k_tr(const float* __restrict__ x,
                                            unsigned int* __restrict__ xt_u32,
                                            const float* __restrict__ w,
                                            const float* __restrict__ w_off,
                                            unsigned short* __restrict__ wfrag,
                                            unsigned short* __restrict__ wb) {
  __shared__ float tile[64 * 129];
  int blk = blockIdx.x;                   // b*128 + h
  int tid = threadIdx.x;
  int gi = blk * 256 + tid;

  // ---- folded prep ----
  if (blk < 144) {
    if (gi < 36864) {                     // 72 frags * 512
      int j = gi & 7, lane = (gi >> 3) & 63, f = gi >> 9;
      int kk = f & 1, ot = (f >> 1) & 3, t = f >> 3;
      int o = ot * 16 + (lane & 15);
      int c = (kk * 4 + (lane >> 4)) * 8 + j;
      wfrag[gi] = f2bf(w[o * 576 + c * 9 + t]);
    }
    if (gi < 18432) {
      int j = gi & 7, lane = (gi >> 3) & 63, f = gi >> 9;
      int n = f & 1, kk = (f >> 1) & 1, t = f >> 2;
      int o = n * 16 + (lane & 15);
      int c = kk * 32 + (lane >> 4) * 8 + j;
      float v = (o < 18) ? w_off[o * 576 + c * 9 + t] : 0.0f;
      wb[gi] = f2bf(v);
    }
  }
  // ---- folded border zero: 2064 cells * 8 int4 ----
  if (gi < 16512) {
    int c4 = gi & 7, ci = gi >> 3;
    int b = ci / 516, cell = ci - b * 516;
    int row, col;
    if (cell < 130)      { row = 0;   col = cell; }
    else if (cell < 260) { row = 129; col = cell - 130; }
    else { int k = cell - 260; row = 1 + (k >> 1); col = (k & 1) ? 129 : 0; }
    reinterpret_cast<int4*>(xt_u32 + ((size_t)(b * PW + row) * PW + col) * 32)[c4] =
        make_int4(0, 0, 0, 0);
  }

  // ---- transpose (r8-verified) ----
  int h = blk & 127, b = blk >> 7;
  int w0 = tid & 127, ch = tid >> 7;
  const float* xb = x + ((size_t)b * 64 * HW + h) * HW;
#pragma unroll
  for (int k = 0; k < 32; ++k) {
    int c = ch * 32 + k;
    tile[c * 129 + (w0 ^ (c & 1))] = xb[c * (HW * HW) + w0];
  }
  __syncthreads();
  int c2 = tid & 31, wg = tid >> 5;
#pragma unroll
  for (int k = 0; k < 16; ++k) {
    int ww = wg * 16 + k;
    float lo = tile[(2 * c2) * 129 + ww];
    float hi = tile[(2 * c2 + 1) * 129 + (ww ^ 1)];
    xt_u32[((size_t)(b * PW + h + 1) * PW + (ww + 1)) * 32 + c2] =
        (unsigned int)f2bf(lo) | ((unsigned int)f2bf(hi) << 16);
  }
}

// ---------------- k_fuse: phase-0 offsets conv + VMEM gather + MFMA GEMM ----------------
// r9 gather structure (global loads, 1 tap ahead, latency hidden by TLP) +
// r10's register-fragment B (no ldsB, no in-loop vmcnt).
// LDS 29952 B -> 5 blocks/CU:
//   [0, 25344)  phase-0 slab 3x66x128B  (union with A dbuf [0,16384) in main loop)
//   [25344, 29952)  loff 64x18 f32
__global__ __launch_bounds__(256) void k_fuse(const unsigned short* __restrict__ xt,
                                              const unsigned short* __restrict__ wb,
                                              const unsigned short* __restrict__ wfrag,
                                              const float* __restrict__ b_off,
                                              const float* __restrict__ bias,
                                              float* __restrict__ out) {
  __shared__ __align__(16) char u_lds[29952];
  char* slab_b = u_lds;
  unsigned short* slab_us = (unsigned short*)u_lds;
  float* loff = (float*)(u_lds + 25344);

  int bid = blockIdx.x;
  bid = (bid & 7) * 128 + (bid >> 3);     // XCD swizzle (1024 % 8 == 0)
  int pix0 = bid * 64;
  int h = (pix0 >> 7) & 127, b = pix0 >> 14, wbase = pix0 & 127;

  int tid = threadIdx.x;
  int wid = tid >> 6, lane = tid & 63;
  int l15 = lane & 15, l4 = lane >> 4;
  int wm = wid >> 1, wn = wid & 1;
  int g = tid & 7, p2 = tid >> 3;

  const unsigned short* xb  = xt + (size_t)b * (PW * PW * 64);
  const unsigned short* xtb = xb + g * 8;

  // ======== phase 0: offsets conv (r8/r9-verified) ========
  // stage 3x66 slab: storage row S = r*66+u covers (padded yp=h+r, xp=wbase+u)
  for (int i = wid; i < 25; i += 4) {
    int e = i * 512 + lane * 8;
    if (e < 12672) {
      int S = e >> 6, c8 = (e >> 3) & 7;
      int r = S / 66, u = S - r * 66;
      gld_lds16(xb + ((size_t)((h + r) * PW + wbase + u)) * 64 + ((c8 ^ (S & 7)) << 3),
                &slab_us[i * 512]);
    }
  }

  const int4* wb4 = reinterpret_cast<const int4*>(wb);
  int4 bc[4], bn[4];
#pragma unroll
  for (int q = 0; q < 4; ++q) bc[q] = wb4[q * 64 + lane];
  asm volatile("s_waitcnt vmcnt(0)" ::: "memory");
  __builtin_amdgcn_s_barrier();

  f32x4 acc0 = {0.f, 0.f, 0.f, 0.f}, acc1 = {0.f, 0.f, 0.f, 0.f};
#pragma unroll 1
  for (int t = 0; t < 9; ++t) {
    if (t < 8) {
#pragma unroll
      for (int q = 0; q < 4; ++q) bn[q] = wb4[((t + 1) * 4 + q) * 64 + lane];
    }
    int ti = t / 3, tj = t - ti * 3;
    int S = ti * 66 + (wid * 16 + l15) + tj;
#pragma unroll
    for (int kk = 0; kk < 2; ++kk) {
      int phys = (kk * 4 + l4) ^ (S & 7);
      bf16x8 a = *reinterpret_cast<const bf16x8*>(slab_b + S * 128 + phys * 16);
      acc0 = __builtin_amdgcn_mfma_f32_16x16x32_bf16(a, *(const bf16x8*)&bc[kk * 2 + 0], acc0, 0, 0, 0);
      acc1 = __builtin_amdgcn_mfma_f32_16x16x32_bf16(a, *(const bf16x8*)&bc[kk * 2 + 1], acc1, 0, 0, 0);
    }
#pragma unroll
    for (int q = 0; q < 4; ++q) bc[q] = bn[q];
  }
  {
    float bo0 = b_off[l15];
    int pl = wid * 16 + l4 * 4;
#pragma unroll
    for (int reg = 0; reg < 4; ++reg)
      loff[(pl + reg) * 18 + l15] = acc0[reg] + bo0;
    if (l15 < 2) {
      float bo1 = b_off[16 + l15];
#pragma unroll
      for (int reg = 0; reg < 4; ++reg)
        loff[(pl + reg) * 18 + 16 + l15] = acc1[reg] + bo1;
    }
  }
  __syncthreads();   // slab reads done (union overwritten next) + loff visible

  // ======== main loop: VMEM gather (r9-verified) + reg-B MFMA ========
  auto ldsAp = [&](int s) { return (unsigned short*)(u_lds + s * 8192); };

  int4 r[2][4];
  float fw[2][4];

  auto gather = [&](int t) {
    int ti = t / 3, tj = t % 3;
#pragma unroll
    for (int k = 0; k < 2; ++k) {
      int pp = p2 + 32 * k;
      float2 d = *reinterpret_cast<const float2*>(&loff[pp * 18 + 2 * t]);
      float py = (float)(h + ti - 1) + d.x;
      float px = (float)(wbase + pp + tj - 1) + d.y;
      float y0f = floorf(py), x0f = floorf(px);
      float wy = py - y0f, wxf = px - x0f;
      int y0 = (int)y0f, x0 = (int)x0f;
      int y1 = y0 + 1, x1 = x0 + 1;
      fw[k][0] = (((unsigned)y0 < HW) && ((unsigned)x0 < HW)) ? (1.f - wy) * (1.f - wxf) : 0.f;
      fw[k][1] = (((unsigned)y0 < HW) && ((unsigned)x1 < HW)) ? (1.f - wy) * wxf : 0.f;
      fw[k][2] = (((unsigned)y1 < HW) && ((unsigned)x0 < HW)) ? wy * (1.f - wxf) : 0.f;
      fw[k][3] = (((unsigned)y1 < HW) && ((unsigned)x1 < HW)) ? wy * wxf : 0.f;
      int y0c = min(max(y0, 0), HW - 1) + 1, y1c = min(max(y1, 0), HW - 1) + 1;
      int x0c = min(max(x0, 0), HW - 1) + 1, x1c = min(max(x1, 0), HW - 1) + 1;
      r[k][0] = *reinterpret_cast<const int4*>(xtb + ((size_t)y0c * PW + x0c) * 64);
      r[k][1] = *reinterpret_cast<const int4*>(xtb + ((size_t)y0c * PW + x1c) * 64);
      r[k][2] = *reinterpret_cast<const int4*>(xtb + ((size_t)y1c * PW + x0c) * 64);
      r[k][3] = *reinterpret_cast<const int4*>(xtb + ((size_t)y1c * PW + x1c) * 64);
    }
  };

  auto lerp_write = [&](int bsel) {
#pragma unroll
    for (int k = 0; k < 2; ++k) {
      int pp = p2 + 32 * k;
      float v00[8], v01[8], v10[8], v11[8];
      bf8_to_f32(r[k][0], v00); bf8_to_f32(r[k][1], v01);
      bf8_to_f32(r[k][2], v10); bf8_to_f32(r[k][3], v11);
      unsigned int pk[4];
#pragma unroll
      for (int j = 0; j < 4; ++j) {
        float slo = fmaf(v11[2 * j], fw[k][3],
                    fmaf(v10[2 * j], fw[k][2],
                    fmaf(v01[2 * j], fw[k][1], v00[2 * j] * fw[k][0])));
        float shi = fmaf(v11[2 * j + 1], fw[k][3],
                    fmaf(v10[2 * j + 1], fw[k][2],
                    fmaf(v01[2 * j + 1], fw[k][1], v00[2 * j + 1] * fw[k][0])));
        pk[j] = (unsigned int)f2bf(slo) | ((unsigned int)f2bf(shi) << 16);
      }
      *reinterpret_cast<int4*>(&ldsAp(bsel)[pp * 64 + ((g ^ (pp & 7)) << 3)]) =
          *reinterpret_cast<int4*>(pk);
    }
  };

  // main-GEMM B frags (r10-verified layout): Bc[fn*2+kk], frag = t*8 + (wn*2+fn)*2 + kk
  const int4* wf4 = reinterpret_cast<const int4*>(wfrag);
  int4 Bc[4], Bn[4];
#pragma unroll
  for (int q = 0; q < 4; ++q) {
    int fn = q >> 1, kk = q & 1;
    Bc[q] = wf4[((wn * 2 + fn) * 2 + kk) * 64 + lane];
  }

  f32x4 acc00 = {0.f, 0.f, 0.f, 0.f}, acc01 = {0.f, 0.f, 0.f, 0.f};
  f32x4 acc10 = {0.f, 0.f, 0.f, 0.f}, acc11 = {0.f, 0.f, 0.f, 0.f};

  gather(0);
  lerp_write(0);
  __syncthreads();                 // A0 ready

#pragma unroll 1
  for (int t = 0; t < 9; ++t) {
    int cur = t & 1;
    if (t < 8) {
#pragma unroll
      for (int q = 0; q < 4; ++q) {
        int fn = q >> 1, kk = q & 1;
        Bn[q] = wf4[(((t + 1) * 4 + wn * 2 + fn) * 2 + kk) * 64 + lane];
      }
      gather(t + 1);               // VMEM loads in flight under MFMA
    }
    const char* Ab = (const char*)ldsAp(cur);
#pragma unroll
    for (int kk = 0; kk < 2; ++kk) {
      int sw = (((kk * 4 + l4) ^ (l15 & 7)) << 4) + l15 * 128;
      bf16x8 a0 = *(const bf16x8*)(Ab + (wm * 32 + 0)  * 128 + sw);
      bf16x8 a1 = *(const bf16x8*)(Ab + (wm * 32 + 16) * 128 + sw);
      acc00 = __builtin_amdgcn_mfma_f32_16x16x32_bf16(a0, *(const bf16x8*)&Bc[0 * 2 + kk], acc00, 0, 0, 0);
      acc01 = __builtin_amdgcn_mfma_f32_16x16x32_bf16(a0, *(const bf16x8*)&Bc[1 * 2 + kk], acc01, 0, 0, 0);
      acc10 = __builtin_amdgcn_mfma_f32_16x16x32_bf16(a1, *(const bf16x8*)&Bc[0 * 2 + kk], acc10, 0, 0, 0);
      acc11 = __builtin_amdgcn_mfma_f32_16x16x32_bf16(a1, *(const bf16x8*)&Bc[1 * 2 + kk], acc11, 0, 0, 0);
    }
    if (t < 8) lerp_write(cur ^ 1);  // compiler waits gather vmcnt here
#pragma unroll
    for (int q = 0; q < 4; ++q) Bc[q] = Bn[q];
    __syncthreads();
  }

  int m0 = wm * 32 + (l4 << 2);
#pragma unroll
  for (int fm = 0; fm < 2; ++fm) {
#pragma unroll
    for (int fn = 0; fn < 2; ++fn) {
      f32x4 a = (fm == 0) ? ((fn == 0) ? acc00 : acc01) : ((fn == 0) ? acc10 : acc11);
      int o = wn * 32 + fn * 16 + l15;
      int pix = pix0 + m0 + fm * 16;
      int bb = pix >> 14, hw = pix & 16383;
      float bz = bias[o];
      float4 st = make_float4(a[0] + bz, a[1] + bz, a[2] + bz, a[3] + bz);
      *reinterpret_cast<float4*>(&out[(((size_t)bb * 64 + o) << 14) + hw]) = st;
    }
  }
}

extern "C" void kernel_launch(void* const* d_in, const int* in_sizes, int n_in,
                              void* d_out, int out_size, void* d_ws, size_t ws_size,
                              hipStream_t stream) {
  const float* x     = (const float*)d_in[0];
  const float* w_off = (const float*)d_in[1];
  const float* b_off = (const float*)d_in[2];
  const float* w     = (const float*)d_in[3];
  const float* bias  = (const float*)d_in[4];
  float* out = (float*)d_out;
  char* ws   = (char*)d_ws;

  // ws layout (BYTES):
  //   wfrag [0,       73,728)      36,864 bf16 (main-GEMM B, frag-ordered)
  //   wb    [73,728,  110,592)     18,432 bf16 (offsets-conv B frags)
  //   xt    [110,592, 8,763,392)   4*130*130*64 bf16 (padded, zero border)
  unsigned short* wfrag = (unsigned short*)(ws);
  unsigned short* wb    = (unsigned short*)(ws + 73728);
  unsigned short* xt    = (unsigned short*)(ws + 110592);

  hipLaunchKernelGGL(k_tr,   dim3(512),  dim3(256), 0, stream,
                     x, (unsigned int*)xt, w, w_off, wfrag, wb);
  hipLaunchKernelGGL(k_fuse, dim3(1024), dim3(256), 0, stream,
                     xt, wb, wfrag, b_off, bias, out);
}